// Round 1
// baseline (1432.864 us; speedup 1.0000x reference)
//
#include <hip/hip_runtime.h>

#define N_NODES 100000
#define N_EDGES 1200000
#define D 64
#define NPB 32   // nodes per block in MLP kernel

// ---------------------------------------------------------------------------
// Phase 1: msg = node_feat[src] + edge_feat ; agg[dst] += msg  (atomic scatter)
// 16 threads per edge, float4 per thread (64 floats = 256 B per edge).
// ---------------------------------------------------------------------------
__global__ __launch_bounds__(256) void scatter_kernel(
    const float* __restrict__ node_feat,
    const float* __restrict__ edge_feat,
    const int* __restrict__ src_idx,
    const int* __restrict__ dst_idx,
    float* __restrict__ agg) {
    long long tid = (long long)blockIdx.x * blockDim.x + threadIdx.x;
    int e = (int)(tid >> 4);
    if (e >= N_EDGES) return;
    int f = (int)(tid & 15) << 2;   // feature offset (float4 granularity)

    int s = src_idx[e];
    int d = dst_idx[e];

    const float4 nf = *(const float4*)(node_feat + (long long)s * D + f);
    const float4 ef = *(const float4*)(edge_feat + (long long)e * D + f);

    float* o = agg + (long long)d * D + f;
    atomicAdd(o + 0, nf.x + ef.x);
    atomicAdd(o + 1, nf.y + ef.y);
    atomicAdd(o + 2, nf.z + ef.z);
    atomicAdd(o + 3, nf.w + ef.w);
}

// ---------------------------------------------------------------------------
// Phase 2: out = relu(agg @ W1 + b1) @ W2 + b2
// 32 nodes per 256-thread block; agg & h tiles staged in LDS; W from L1/L2.
// ---------------------------------------------------------------------------
__global__ __launch_bounds__(256) void mlp_kernel(
    const float* __restrict__ agg,
    const float* __restrict__ W1, const float* __restrict__ b1,
    const float* __restrict__ W2, const float* __restrict__ b2,
    float* __restrict__ out) {
    __shared__ float s_agg[NPB][D];     // 8 KB
    __shared__ float s_h[NPB][2 * D];   // 16 KB

    const int tid = threadIdx.x;
    const long long base = (long long)blockIdx.x * NPB;

    // Load agg tile: 2048 floats, 256 threads -> 8 each, fully coalesced.
    for (int i = tid; i < NPB * D; i += 256) {
        long long n = base + i / D;
        s_agg[0][i] = (n < N_NODES) ? agg[n * D + (i % D)] : 0.0f;
    }
    __syncthreads();

    // h = relu(agg @ W1 + b1): NPB x 128 outputs, 256 threads -> 16 each.
    {
        const int j = tid & 127;       // h feature
        const int g = tid >> 7;        // node subset (0/1)
        float acc[NPB / 2];
        const float bias = b1[j];
        #pragma unroll
        for (int i = 0; i < NPB / 2; i++) acc[i] = bias;
        for (int d = 0; d < D; d++) {
            float w = W1[d * 128 + j];            // coalesced
            #pragma unroll
            for (int i = 0; i < NPB / 2; i++)
                acc[i] = fmaf(s_agg[g + 2 * i][d], w, acc[i]);  // LDS broadcast
        }
        #pragma unroll
        for (int i = 0; i < NPB / 2; i++)
            s_h[g + 2 * i][j] = fmaxf(acc[i], 0.0f);
    }
    __syncthreads();

    // out = h @ W2 + b2: NPB x 64 outputs, 256 threads -> 8 each.
    {
        const int k = tid & 63;        // out feature
        const int g = tid >> 6;        // node subset (0..3)
        float acc[NPB / 4];
        const float bias = b2[k];
        #pragma unroll
        for (int i = 0; i < NPB / 4; i++) acc[i] = bias;
        for (int j = 0; j < 2 * D; j++) {
            float w = W2[j * 64 + k];             // coalesced
            #pragma unroll
            for (int i = 0; i < NPB / 4; i++)
                acc[i] = fmaf(s_h[g + 4 * i][j], w, acc[i]);    // LDS broadcast
        }
        #pragma unroll
        for (int i = 0; i < NPB / 4; i++) {
            long long n = base + g + 4 * i;
            if (n < N_NODES) out[n * D + k] = acc[i];           // coalesced
        }
    }
}

extern "C" void kernel_launch(void* const* d_in, const int* in_sizes, int n_in,
                              void* d_out, int out_size, void* d_ws, size_t ws_size,
                              hipStream_t stream) {
    const float* node_feat = (const float*)d_in[0];
    const float* edge_feat = (const float*)d_in[1];
    const int*   edge_index = (const int*)d_in[2];   // [2, E]: row0 = src, row1 = dst
    const float* W1 = (const float*)d_in[3];
    const float* b1 = (const float*)d_in[4];
    const float* W2 = (const float*)d_in[5];
    const float* b2 = (const float*)d_in[6];
    float* out = (float*)d_out;
    float* agg = (float*)d_ws;   // N_NODES * D floats = 25.6 MB scratch

    // ws is re-poisoned to 0xAA before every timed launch — must zero each call.
    hipMemsetAsync(agg, 0, (size_t)N_NODES * D * sizeof(float), stream);

    const long long scatter_threads = (long long)N_EDGES * 16;
    const int scatter_blocks = (int)((scatter_threads + 255) / 256);
    scatter_kernel<<<scatter_blocks, 256, 0, stream>>>(
        node_feat, edge_feat, edge_index, edge_index + N_EDGES, agg);

    const int mlp_blocks = (N_NODES + NPB - 1) / NPB;
    mlp_kernel<<<mlp_blocks, 256, 0, stream>>>(agg, W1, b1, W2, b2, out);
}

// Round 2
// 836.325 us; speedup vs baseline: 1.7133x; 1.7133x over previous
//
#include <hip/hip_runtime.h>

#define N_NODES 100000
#define N_EDGES 1200000
#define D 64
#define D2 128
#define NPB 32          // nodes per block in fused gather+MLP
#define SCAN_BLK 256
#define N_SCAN_BLKS ((N_NODES + SCAN_BLK - 1) / SCAN_BLK)   // 391
#define CNT_PAD 100352  // multiple of 256, >= N_NODES

// ws layout (int32 units):
//   [0]                 counts   (CNT_PAD)   -- must be zeroed each call
//   [CNT_PAD]           offsets  (CNT_PAD)
//   [2*CNT_PAD]         cursors  (CNT_PAD)
//   [3*CNT_PAD]         partials (512)
//   [3*CNT_PAD+512]     scanned  (512)
//   [3*CNT_PAD+1024]    buckets  (int2 x N_EDGES)  -- (src, edge_id)
// total ~10.8 MB (< 25.6 MB proven available in round 1)

__global__ __launch_bounds__(256) void hist_kernel(
    const int* __restrict__ dst, int* __restrict__ counts) {
    int e = blockIdx.x * 256 + threadIdx.x;
    if (e < N_EDGES) atomicAdd(&counts[dst[e]], 1);
}

__global__ __launch_bounds__(SCAN_BLK) void scan1_kernel(
    const int* __restrict__ counts, int* __restrict__ offsets,
    int* __restrict__ partials) {
    __shared__ int s[2][SCAN_BLK];
    int t = threadIdx.x, i = blockIdx.x * SCAN_BLK + t;
    int c = (i < N_NODES) ? counts[i] : 0;
    int pin = 0;
    s[0][t] = c; __syncthreads();
    for (int off = 1; off < SCAN_BLK; off <<= 1) {
        int v = s[pin][t] + ((t >= off) ? s[pin][t - off] : 0);
        s[pin ^ 1][t] = v; pin ^= 1; __syncthreads();
    }
    int incl = s[pin][t];
    if (i < N_NODES) offsets[i] = incl - c;          // block-local exclusive
    if (t == SCAN_BLK - 1) partials[blockIdx.x] = incl;
}

__global__ __launch_bounds__(512) void scan2_kernel(
    const int* __restrict__ partials, int* __restrict__ scanned) {
    __shared__ int s[2][512];
    int t = threadIdx.x;
    int c = (t < N_SCAN_BLKS) ? partials[t] : 0;
    int pin = 0;
    s[0][t] = c; __syncthreads();
    for (int off = 1; off < 512; off <<= 1) {
        int v = s[pin][t] + ((t >= off) ? s[pin][t - off] : 0);
        s[pin ^ 1][t] = v; pin ^= 1; __syncthreads();
    }
    if (t < N_SCAN_BLKS) scanned[t] = s[pin][t] - c;  // exclusive
}

__global__ __launch_bounds__(SCAN_BLK) void scan3_kernel(
    int* __restrict__ offsets, int* __restrict__ cursors,
    const int* __restrict__ scanned) {
    int i = blockIdx.x * SCAN_BLK + threadIdx.x;
    if (i < N_NODES) {
        int o = offsets[i] + scanned[blockIdx.x];
        offsets[i] = o;
        cursors[i] = o;
    }
}

__global__ __launch_bounds__(256) void bucket_kernel(
    const int* __restrict__ src, const int* __restrict__ dst,
    int* __restrict__ cursors, int2* __restrict__ buckets) {
    int e = blockIdx.x * 256 + threadIdx.x;
    if (e < N_EDGES) {
        int d = dst[e];
        int pos = atomicAdd(&cursors[d], 1);
        buckets[pos] = make_int2(src[e], e);
    }
}

__device__ __forceinline__ void fma4(float4& acc, float s, const float4& w) {
    acc.x = fmaf(s, w.x, acc.x); acc.y = fmaf(s, w.y, acc.y);
    acc.z = fmaf(s, w.z, acc.z); acc.w = fmaf(s, w.w, acc.w);
}

// One wave per node gathers msg-sum into LDS; then block-wide register-blocked MLP.
__global__ __launch_bounds__(256) void gather_mlp_kernel(
    const float* __restrict__ nf, const float* __restrict__ ef,
    const int* __restrict__ offsets, const int* __restrict__ counts,
    const int2* __restrict__ buckets,
    const float* __restrict__ W1, const float* __restrict__ b1,
    const float* __restrict__ W2, const float* __restrict__ b2,
    float* __restrict__ out) {
    __shared__ float s_agg[NPB][D + 4];    // pad 4: conflict-free b128 reads
    __shared__ float s_h[NPB][D2 + 4];

    const int tid = threadIdx.x;
    const int lane = tid & 63;
    const int wv = tid >> 6;               // wave 0..3
    const int base = blockIdx.x * NPB;     // 3125*32 == 100000 exactly

    // ---- gather: wave wv owns LDS rows wv*8 .. wv*8+7 ----
    for (int r = 0; r < 8; r++) {
        int slot = wv * 8 + r;
        int n = base + slot;
        int off = offsets[n];
        int cnt = counts[n];
        float acc = 0.0f;
        for (int i = 0; i < cnt; i++) {
            int2 p = buckets[off + i];     // same addr all lanes -> broadcast
            acc += nf[(long long)p.x * D + lane] + ef[(long long)p.y * D + lane];
        }
        s_agg[slot][lane] = acc;
    }
    __syncthreads();

    // ---- layer 1: h = relu(agg @ W1 + b1), tile = 4 nodes x 4 j per thread ----
    {
        const int jg = tid & 31, ng = tid >> 5;
        const int j0 = jg * 4, n0 = ng * 4;
        float4 bb = *(const float4*)(b1 + j0);
        float4 acc0 = bb, acc1 = bb, acc2 = bb, acc3 = bb;
        for (int d = 0; d < D; d += 4) {
            float4 a0 = *(const float4*)&s_agg[n0 + 0][d];
            float4 a1 = *(const float4*)&s_agg[n0 + 1][d];
            float4 a2 = *(const float4*)&s_agg[n0 + 2][d];
            float4 a3 = *(const float4*)&s_agg[n0 + 3][d];
            float4 w0 = *(const float4*)(W1 + (d + 0) * D2 + j0);
            float4 w1 = *(const float4*)(W1 + (d + 1) * D2 + j0);
            float4 w2 = *(const float4*)(W1 + (d + 2) * D2 + j0);
            float4 w3 = *(const float4*)(W1 + (d + 3) * D2 + j0);
            fma4(acc0, a0.x, w0); fma4(acc0, a0.y, w1); fma4(acc0, a0.z, w2); fma4(acc0, a0.w, w3);
            fma4(acc1, a1.x, w0); fma4(acc1, a1.y, w1); fma4(acc1, a1.z, w2); fma4(acc1, a1.w, w3);
            fma4(acc2, a2.x, w0); fma4(acc2, a2.y, w1); fma4(acc2, a2.z, w2); fma4(acc2, a2.w, w3);
            fma4(acc3, a3.x, w0); fma4(acc3, a3.y, w1); fma4(acc3, a3.z, w2); fma4(acc3, a3.w, w3);
        }
        float4 z = make_float4(0.f, 0.f, 0.f, 0.f);
        float4 r0 = make_float4(fmaxf(acc0.x,z.x), fmaxf(acc0.y,z.y), fmaxf(acc0.z,z.z), fmaxf(acc0.w,z.w));
        float4 r1 = make_float4(fmaxf(acc1.x,z.x), fmaxf(acc1.y,z.y), fmaxf(acc1.z,z.z), fmaxf(acc1.w,z.w));
        float4 r2 = make_float4(fmaxf(acc2.x,z.x), fmaxf(acc2.y,z.y), fmaxf(acc2.z,z.z), fmaxf(acc2.w,z.w));
        float4 r3 = make_float4(fmaxf(acc3.x,z.x), fmaxf(acc3.y,z.y), fmaxf(acc3.z,z.z), fmaxf(acc3.w,z.w));
        *(float4*)&s_h[n0 + 0][j0] = r0;
        *(float4*)&s_h[n0 + 1][j0] = r1;
        *(float4*)&s_h[n0 + 2][j0] = r2;
        *(float4*)&s_h[n0 + 3][j0] = r3;
    }
    __syncthreads();

    // ---- layer 2: out = h @ W2 + b2, tile = 2 nodes x 4 k per thread ----
    {
        const int kg = tid & 15, ng = tid >> 4;
        const int k0 = kg * 4, n0 = ng * 2;
        float4 bb = *(const float4*)(b2 + k0);
        float4 o0 = bb, o1 = bb;
        for (int j = 0; j < D2; j += 4) {
            float4 h0 = *(const float4*)&s_h[n0 + 0][j];
            float4 h1 = *(const float4*)&s_h[n0 + 1][j];
            float4 w0 = *(const float4*)(W2 + (j + 0) * D + k0);
            float4 w1 = *(const float4*)(W2 + (j + 1) * D + k0);
            float4 w2 = *(const float4*)(W2 + (j + 2) * D + k0);
            float4 w3 = *(const float4*)(W2 + (j + 3) * D + k0);
            fma4(o0, h0.x, w0); fma4(o0, h0.y, w1); fma4(o0, h0.z, w2); fma4(o0, h0.w, w3);
            fma4(o1, h1.x, w0); fma4(o1, h1.y, w1); fma4(o1, h1.z, w2); fma4(o1, h1.w, w3);
        }
        long long na = base + n0;
        *(float4*)(out + na * D + k0) = o0;
        *(float4*)(out + (na + 1) * D + k0) = o1;
    }
}

extern "C" void kernel_launch(void* const* d_in, const int* in_sizes, int n_in,
                              void* d_out, int out_size, void* d_ws, size_t ws_size,
                              hipStream_t stream) {
    const float* node_feat = (const float*)d_in[0];
    const float* edge_feat = (const float*)d_in[1];
    const int*   edge_index = (const int*)d_in[2];   // [2, E]: row0=src, row1=dst
    const float* W1 = (const float*)d_in[3];
    const float* b1 = (const float*)d_in[4];
    const float* W2 = (const float*)d_in[5];
    const float* b2 = (const float*)d_in[6];
    float* out = (float*)d_out;

    const int* src = edge_index;
    const int* dst = edge_index + N_EDGES;

    int* counts   = (int*)d_ws;
    int* offsets  = counts + CNT_PAD;
    int* cursors  = counts + 2 * CNT_PAD;
    int* partials = counts + 3 * CNT_PAD;
    int* scanned  = partials + 512;
    int2* buckets = (int2*)(scanned + 512);

    // ws is re-poisoned each call: zero the histogram.
    hipMemsetAsync(counts, 0, CNT_PAD * sizeof(int), stream);

    const int eblocks = (N_EDGES + 255) / 256;
    hist_kernel<<<eblocks, 256, 0, stream>>>(dst, counts);
    scan1_kernel<<<N_SCAN_BLKS, SCAN_BLK, 0, stream>>>(counts, offsets, partials);
    scan2_kernel<<<1, 512, 0, stream>>>(partials, scanned);
    scan3_kernel<<<N_SCAN_BLKS, SCAN_BLK, 0, stream>>>(offsets, cursors, scanned);
    bucket_kernel<<<eblocks, 256, 0, stream>>>(src, dst, cursors, buckets);

    gather_mlp_kernel<<<N_NODES / NPB, 256, 0, stream>>>(
        node_feat, edge_feat, offsets, counts, buckets, W1, b1, W2, b2, out);
}